// Round 9
// baseline (136.936 us; speedup 1.0000x reference)
//
#include <hip/hip_runtime.h>
#include <hip/hip_bf16.h>

#define S_ 1024
#define D_ 128
#define V_ 100000
#define N_ 4096
#define VPAD_ 100352    // 3136 strips of 32 rows; pad rows zero -> exp2(0)=1
#define PADROWS_ 352.0f

typedef __attribute__((ext_vector_type(4))) float f32x4;
typedef __attribute__((ext_vector_type(8))) short bf16x8;

#define LOG2E_ 1.4426950408889634f
#define LN2_   0.6931471805599453f

__device__ __forceinline__ void gload16(const void* g, void* l) {
    __builtin_amdgcn_global_load_lds(
        (const __attribute__((address_space(1))) void*)g,
        (__attribute__((address_space(3))) void*)l, 16, 0, 0);
}

__device__ __forceinline__ float exp2_fast(float x) {
#if __has_builtin(__builtin_amdgcn_exp2f)
    return __builtin_amdgcn_exp2f(x);
#else
    return exp2f(x);
#endif
}

// ---- kernel 1: normalize K rows -> bf16, zero-fill pad rows [V_, VPAD_) ----
__global__ void knorm_kernel(const float* __restrict__ K, __hip_bfloat16* __restrict__ Kn) {
    int w = (blockIdx.x * blockDim.x + threadIdx.x) >> 6;
    int lane = threadIdx.x & 63;
    if (w >= VPAD_) return;
    unsigned int* dst = (unsigned int*)(Kn + (size_t)w * D_);
    if (w >= V_) { dst[lane] = 0u; return; }
    float2 v = ((const float2*)(K + (size_t)w * D_))[lane];
    float ss = v.x * v.x + v.y * v.y;
    #pragma unroll
    for (int off = 32; off; off >>= 1) ss += __shfl_xor(ss, off);
    float rn = rsqrtf(ss);
    __hip_bfloat162 o;
    o.x = __float2bfloat16(v.x * rn);
    o.y = __float2bfloat16(v.y * rn);
    ((__hip_bfloat162*)dst)[lane] = o;
}

// ---- kernel 2: gather + normalize Q -> bf16 (pre-scaled by log2 e); zero Ssum ----
__global__ void qnorm_kernel(const float* __restrict__ Q, const int* __restrict__ loc,
                             __hip_bfloat16* __restrict__ Qn, float* __restrict__ Ssum) {
    int w = (blockIdx.x * blockDim.x + threadIdx.x) >> 6;
    int lane = threadIdx.x & 63;
    if (w >= N_) return;
    if (lane == 0) Ssum[w] = 0.f;
    int b = loc[2 * w], s = loc[2 * w + 1];
    float2 v = ((const float2*)(Q + ((size_t)b * S_ + (size_t)s) * D_))[lane];
    float ss = v.x * v.x + v.y * v.y;
    #pragma unroll
    for (int off = 32; off; off >>= 1) ss += __shfl_xor(ss, off);
    float rn = rsqrtf(ss) * LOG2E_;        // exp2 domain
    __hip_bfloat162 o;
    o.x = __float2bfloat16(v.x * rn);
    o.y = __float2bfloat16(v.y * rn);
    ((__hip_bfloat162*)(Qn + (size_t)w * D_))[lane] = o;
}

// ---- kernel 3: main  sum_v exp2(q . k_v)  -- BARRIER-FREE per-wave pipelines ----
// Each wave: independent worker, 64 q-rows x stream of 32-row v-strips.
// Private 2x8KB LDS double buffer per wave (64KB/block). Staging via
// global_load_lds (coalesced; row-XOR swizzle so ds_read_b128 is clean).
// Sync = per-wave counted vmcnt + lgkmcnt only; ZERO barriers. Independent
// waves drift anti-phase -> exp2 (trans pipe) hides under partner's MFMA.
__global__ __launch_bounds__(256, 2) void ce_main(
    const __hip_bfloat16* __restrict__ Qn,
    const __hip_bfloat16* __restrict__ Kn,
    float* __restrict__ Ssum)
{
    __shared__ char klds[65536];   // 4 waves x (2 x 8KB)

    const int tid  = threadIdx.x;
    const int lane = tid & 63;
    const int wv   = tid >> 6;
    const int r0   = lane & 15;
    const int hi   = lane >> 4;
    const int r3   = r0 & 7;

    // XCD swizzle: xcd owns 8 q-strips x 8 phase-groups (same v-window timing)
    const int fid    = blockIdx.y * 64 + blockIdx.x;
    const int xcd    = fid & 7;
    const int idx    = fid >> 3;              // 0..63
    const int qstrip = xcd * 8 + (idx >> 3);  // 0..63 (64 q-rows each)
    const int phase  = (idx & 7) * 4 + wv;    // 0..31: wave's v-strip phase

    // ---- Q fragments -> registers (loop-invariant) ----
    bf16x8 afr[4][4];
    {
        const char* qsrc = (const char*)Qn + (size_t)qstrip * 16384
                         + r0 * 256 + (hi << 4);
        #pragma unroll
        for (int m = 0; m < 4; ++m)
            #pragma unroll
            for (int kk = 0; kk < 4; ++kk)
                afr[m][kk] = *(const bf16x8*)(qsrc + m * 4096 + kk * 64);
    }

    // per-lane swizzled LDS read addresses within the wave's 8KB buffer
    int raddr[2][4];
    #pragma unroll
    for (int nn = 0; nn < 2; ++nn)
        #pragma unroll
        for (int kk = 0; kk < 4; ++kk)
            raddr[nn][kk] = (nn * 16 + r0) * 256 + (((kk * 4 + hi) ^ r3) << 4);

    char* myLds = klds + wv * 16384;          // private; buffers at +0 / +8192
    const char* kvbase = (const char*)Kn + (size_t)phase * 8192;
    // staging source offsets: instr j covers rows 4j..4j+3 of the strip;
    // lane: row=4j+hi, stored slot=r0, src slot = r0 ^ (row&7) = r0^(hi+4(j&1))
    const int gE = hi * 256 + ((r0 ^ hi) << 4);        // even j
    const int gO = hi * 256 + ((r0 ^ (hi + 4)) << 4);  // odd j

#define STAGE(i, BUF) do {                                                   \
        const char* s_ = kvbase + (size_t)(i) * 262144;                      \
        char* d_ = myLds + (BUF);                                            \
        gload16(s_ +    0 + gE, d_ +    0);                                  \
        gload16(s_ + 1024 + gO, d_ + 1024);                                  \
        gload16(s_ + 2048 + gE, d_ + 2048);                                  \
        gload16(s_ + 3072 + gO, d_ + 3072);                                  \
        gload16(s_ + 4096 + gE, d_ + 4096);                                  \
        gload16(s_ + 5120 + gO, d_ + 5120);                                  \
        gload16(s_ + 6144 + gE, d_ + 6144);                                  \
        gload16(s_ + 7168 + gO, d_ + 7168);                                  \
    } while (0)

#define MFMAS(ACC) do {                                                      \
        __builtin_amdgcn_s_setprio(1);                                       \
        _Pragma("unroll")                                                    \
        for (int m = 0; m < 4; ++m) {                                        \
            ACC[m][0] = __builtin_amdgcn_mfma_f32_16x16x32_bf16(afr[m][0], b_[0][0], fz, 0, 0, 0); \
            ACC[m][1] = __builtin_amdgcn_mfma_f32_16x16x32_bf16(afr[m][0], b_[1][0], fz, 0, 0, 0); \
        }                                                                    \
        _Pragma("unroll")                                                    \
        for (int kk = 1; kk < 4; ++kk)                                       \
            _Pragma("unroll")                                                \
            for (int m = 0; m < 4; ++m) {                                    \
                ACC[m][0] = __builtin_amdgcn_mfma_f32_16x16x32_bf16(afr[m][kk], b_[0][kk], ACC[m][0], 0, 0, 0); \
                ACC[m][1] = __builtin_amdgcn_mfma_f32_16x16x32_bf16(afr[m][kk], b_[1][kk], ACC[m][1], 0, 0, 0); \
            }                                                                \
        __builtin_amdgcn_s_setprio(0);                                       \
    } while (0)

#define EXP2S(ACC) do {                                                      \
        _Pragma("unroll")                                                    \
        for (int m = 0; m < 4; ++m)                                          \
            _Pragma("unroll")                                                \
            for (int q = 0; q < 4; ++q)                                      \
                psum[m][q] += exp2_fast(ACC[m][0][q]) + exp2_fast(ACC[m][1][q]); \
    } while (0)

#define DSREAD(BUF) do {                                                     \
        _Pragma("unroll")                                                    \
        for (int nn = 0; nn < 2; ++nn)                                       \
            _Pragma("unroll")                                                \
            for (int kk = 0; kk < 4; ++kk)                                   \
                b_[nn][kk] = *(const bf16x8*)(myLds + (BUF) + raddr[nn][kk]);\
    } while (0)

    // phase: read buf, exp2 prev acc bank (fills ds latency), drain lgkm,
    // re-stage the SAME buf for i+2 (its reads have retired), MFMA, then
    // counted vmcnt(8) so the OTHER buf's stage is retired for next phase.
#define PHASE(BUF, inext, ACC, PRV) do {                                     \
        bf16x8 b_[2][4];                                                     \
        DSREAD(BUF);                                                         \
        EXP2S(PRV);                                                          \
        asm volatile("s_waitcnt lgkmcnt(0)" ::: "memory");                   \
        __builtin_amdgcn_sched_barrier(0);                                   \
        STAGE(inext, BUF);                                                   \
        MFMAS(ACC);                                                          \
        asm volatile("s_waitcnt vmcnt(8)" ::: "memory");                     \
    } while (0)

    float psum[4][4];
    #pragma unroll
    for (int m = 0; m < 4; ++m)
        #pragma unroll
        for (int q = 0; q < 4; ++q) psum[m][q] = 0.f;

    const f32x4 fz = {0.f, 0.f, 0.f, 0.f};
    f32x4 accE[4][2], accO[4][2];
    #pragma unroll
    for (int m = 0; m < 4; ++m)
        #pragma unroll
        for (int nn = 0; nn < 2; ++nn)
            accO[m][nn] = (f32x4){-16384.f, -16384.f, -16384.f, -16384.f}; // exp2 -> 0

    // ---- prologue: stage strips 0 (bufA) and 1 (bufB); wait bufA ready ----
    STAGE(0, 0);
    STAGE(1, 8192);
    asm volatile("s_waitcnt vmcnt(8)" ::: "memory");   // strip 0 resident

    #pragma unroll 1
    for (int i = 0; i < 96; i += 2) {
        PHASE(0,    i + 2, accE, accO);   // strip i   from bufA; stage i+2
        PHASE(8192, i + 3, accO, accE);   // strip i+1 from bufB; stage i+3
    }
    // epilogue: strips 96 (bufA; already resident) and 97 (bufB; 8 in flight)
    {
        bf16x8 b_[2][4];
        DSREAD(0);
        EXP2S(accO);
        asm volatile("s_waitcnt lgkmcnt(0)" ::: "memory");
        __builtin_amdgcn_sched_barrier(0);
        MFMAS(accE);
        asm volatile("s_waitcnt vmcnt(0)" ::: "memory");   // strip 97 resident
        DSREAD(8192);
        EXP2S(accE);
        asm volatile("s_waitcnt lgkmcnt(0)" ::: "memory");
        __builtin_amdgcn_sched_barrier(0);
        MFMAS(accO);
        EXP2S(accO);
    }

#undef STAGE
#undef MFMAS
#undef EXP2S
#undef DSREAD
#undef PHASE

    // reduce over 16 lanes (same q-rows, different v-cols), then atomics
    #pragma unroll
    for (int m = 0; m < 4; ++m) {
        #pragma unroll
        for (int q = 0; q < 4; ++q) {
            float v = psum[m][q];
            v += __shfl_xor(v, 1);
            v += __shfl_xor(v, 2);
            v += __shfl_xor(v, 4);
            v += __shfl_xor(v, 8);
            if (r0 == 0) {
                int row = qstrip * 64 + m * 16 + hi * 4 + q;
                atomicAdd(&Ssum[row], v);
            }
        }
    }
}

// ---- kernel 4: per-row term = log(S - PADROWS) - true_logit ----
__global__ void term_kernel(const __hip_bfloat16* __restrict__ Qn,
                            const __hip_bfloat16* __restrict__ Kn,
                            const int* __restrict__ labels,
                            const float* __restrict__ Ssum,
                            float* __restrict__ T) {
    int w = (blockIdx.x * blockDim.x + threadIdx.x) >> 6;
    int lane = threadIdx.x & 63;
    if (w >= N_) return;
    int lab = labels[w];
    __hip_bfloat162 q2 = ((const __hip_bfloat162*)(Qn + (size_t)w * D_))[lane];
    __hip_bfloat162 k2 = ((const __hip_bfloat162*)(Kn + (size_t)lab * D_))[lane];
    float d = __bfloat162float(q2.x) * __bfloat162float(k2.x)
            + __bfloat162float(q2.y) * __bfloat162float(k2.y);
    #pragma unroll
    for (int off = 32; off; off >>= 1) d += __shfl_xor(d, off);
    if (lane == 0) T[w] = logf(Ssum[w] - PADROWS_) - d * LN2_;
}

// ---- kernel 5: mean over N ----
__global__ void reduce_kernel(const float* __restrict__ T, float* __restrict__ out) {
    __shared__ float sm[4];
    float s = 0.f;
    for (int i = threadIdx.x; i < N_; i += 256) s += T[i];
    #pragma unroll
    for (int off = 32; off; off >>= 1) s += __shfl_xor(s, off);
    if ((threadIdx.x & 63) == 0) sm[threadIdx.x >> 6] = s;
    __syncthreads();
    if (threadIdx.x == 0) out[0] = (sm[0] + sm[1] + sm[2] + sm[3]) * (1.0f / (float)N_);
}

extern "C" void kernel_launch(void* const* d_in, const int* in_sizes, int n_in,
                              void* d_out, int out_size, void* d_ws, size_t ws_size,
                              hipStream_t stream) {
    (void)in_sizes; (void)n_in; (void)out_size; (void)ws_size;
    const float* Q   = (const float*)d_in[0];
    const float* K   = (const float*)d_in[1];
    const int* loc   = (const int*)d_in[2];
    const int* labels= (const int*)d_in[3];
    float* out = (float*)d_out;

    char* ws = (char*)d_ws;
    __hip_bfloat16* Kn = (__hip_bfloat16*)ws;                       // VPAD_*128*2 = 25,690,112 B
    __hip_bfloat16* Qn = (__hip_bfloat16*)(ws + 25690112);          // N_*128*2   =  1,048,576 B
    float* Ssum        = (float*)(ws + 25690112 + 1048576);         // N_*4
    float* T           = Ssum + N_;                                  // N_*4

    knorm_kernel<<<VPAD_ / 4, 256, 0, stream>>>(K, Kn);
    qnorm_kernel<<<N_ / 4, 256, 0, stream>>>(Q, loc, Qn, Ssum);
    ce_main<<<dim3(64, 8), 256, 0, stream>>>(Qn, Kn, Ssum);
    term_kernel<<<N_ / 4, 256, 0, stream>>>(Qn, Kn, labels, Ssum, T);
    reduce_kernel<<<1, 256, 0, stream>>>(T, out);
}

// Round 10
// 114.738 us; speedup vs baseline: 1.1935x; 1.1935x over previous
//
#include <hip/hip_runtime.h>
#include <hip/hip_bf16.h>

#define S_ 1024
#define D_ 128
#define V_ 100000
#define VSTRIPS_ 3136   // 32-row v-strips; 3125 valid (=100000), 11 zero pads
#define N_ 4096
#define PADROWS_ 352.0f

typedef __attribute__((ext_vector_type(4))) float f32x4;
typedef __attribute__((ext_vector_type(8))) short bf16x8;

#define LOG2E_ 1.4426950408889634f
#define LN2_   0.6931471805599453f

__device__ __forceinline__ float exp2_fast(float x) {
#if __has_builtin(__builtin_amdgcn_exp2f)
    return __builtin_amdgcn_exp2f(x);
#else
    return exp2f(x);
#endif
}

// ---- kernel 1: normalize K -> bf16 in FRAGMENT-MAJOR layout ----
// Strip s (32 rows) occupies 8KB: frag f=nn*4+kk (1KB each), lane l holds
// row nn*16+(l&15), k-bytes kk*64+(l>>4)*16. ce_main then loads B operands
// with perfectly coalesced dwordx4 (no LDS needed there).
// Row r local, byte b: addr = (r>>4)*4096+(b>>6)*1024+((b>>4)&3)*256+(r&15)*16+(b&15)
__global__ void knorm_kernel(const float* __restrict__ K, char* __restrict__ Kn) {
    __shared__ char sm[8192];
    const int strip = blockIdx.x;
    const int tid = threadIdx.x;
    const int lane = tid & 63;
    const int wvv = tid >> 6;
    char* dst = Kn + (size_t)strip * 8192;
    if (strip >= 3125) {                       // zero pad strip
        const f32x4 z = {0.f, 0.f, 0.f, 0.f};
        *(f32x4*)(dst + tid * 32) = z;
        *(f32x4*)(dst + tid * 32 + 16) = z;
        return;
    }
    #pragma unroll
    for (int i = 0; i < 8; ++i) {
        int r = wvv * 8 + i;
        float2 v = ((const float2*)(K + ((size_t)strip * 32 + r) * D_))[lane];
        float ss = v.x * v.x + v.y * v.y;
        #pragma unroll
        for (int off = 32; off; off >>= 1) ss += __shfl_xor(ss, off);
        float rn = rsqrtf(ss);
        __hip_bfloat162 o;
        o.x = __float2bfloat16(v.x * rn);
        o.y = __float2bfloat16(v.y * rn);
        int addr = (r >> 4) * 4096 + (lane >> 4) * 1024 + ((lane >> 2) & 3) * 256
                 + (r & 15) * 16 + (lane & 3) * 4;
        *(__hip_bfloat162*)(sm + addr) = o;
    }
    __syncthreads();
    *(f32x4*)(dst + tid * 32)      = *(const f32x4*)(sm + tid * 32);
    *(f32x4*)(dst + tid * 32 + 16) = *(const f32x4*)(sm + tid * 32 + 16);
}

// ---- kernel 2: gather + normalize Q -> bf16 row-major (pre-scaled log2 e); zero Ssum ----
__global__ void qnorm_kernel(const float* __restrict__ Q, const int* __restrict__ loc,
                             __hip_bfloat16* __restrict__ Qn, float* __restrict__ Ssum) {
    int w = (blockIdx.x * blockDim.x + threadIdx.x) >> 6;
    int lane = threadIdx.x & 63;
    if (w >= N_) return;
    if (lane == 0) Ssum[w] = 0.f;
    int b = loc[2 * w], s = loc[2 * w + 1];
    float2 v = ((const float2*)(Q + ((size_t)b * S_ + (size_t)s) * D_))[lane];
    float ss = v.x * v.x + v.y * v.y;
    #pragma unroll
    for (int off = 32; off; off >>= 1) ss += __shfl_xor(ss, off);
    float rn = rsqrtf(ss) * LOG2E_;        // exp2 domain
    __hip_bfloat162 o;
    o.x = __float2bfloat16(v.x * rn);
    o.y = __float2bfloat16(v.y * rn);
    ((__hip_bfloat162*)(Qn + (size_t)w * D_))[lane] = o;
}

// ---- kernel 3: main  sum_v exp2(q . k_v)  -- NO LDS, NO BARRIERS ----
// Kn is fragment-major: per strip, 8 coalesced dwordx4 = the wave's whole B set.
// Block 256q x 32v (4 waves share the strip stream -> L1/L2 co-hit).
// Wave: 64q x 32v (m=4, nn=2). Register double-buffer, one strip ahead.
// exp2 of the previous strip's acc bank issued between load-issue and MFMA.
__global__ __launch_bounds__(256, 2) void ce_main(
    const __hip_bfloat16* __restrict__ Qn,
    const char* __restrict__ Kn,
    float* __restrict__ Ssum)
{
    const int tid  = threadIdx.x;
    const int lane = tid & 63;
    const int wv   = tid >> 6;
    const int r0   = lane & 15;
    const int hi   = lane >> 4;          // 0..3

    // grid (16,32): XCD owns 4 whole phase-groups (all 16 q-blocks of each)
    const int fid   = blockIdx.y * 16 + blockIdx.x;
    const int xcd   = fid & 7;
    const int idx   = fid >> 3;          // 0..63
    const int phase = xcd * 4 + (idx >> 4);   // 0..31
    const int qb    = idx & 15;          // 0..15 (256 q-rows each)

    // ---- Q fragments -> registers (loop-invariant) ----
    bf16x8 afr[4][4];
    {
        const char* qsrc = (const char*)Qn + ((size_t)qb * 256 + wv * 64 + r0) * 256
                         + (hi << 4);
        #pragma unroll
        for (int m = 0; m < 4; ++m)
            #pragma unroll
            for (int kk = 0; kk < 4; ++kk)
                afr[m][kk] = *(const bf16x8*)(qsrc + m * 4096 + kk * 64);
    }

    // strip j (j=0..97) -> global strip phase + 32*j
    const char* kvbase = Kn + (size_t)phase * 8192 + (lane << 4);

#define LOADSET(R, j) do {                                                   \
        const char* p  = kvbase + (size_t)(j) * 262144;                      \
        const char* p2 = p + 4096;                                           \
        R[0] = *(const bf16x8*)(p);         R[1] = *(const bf16x8*)(p + 1024); \
        R[2] = *(const bf16x8*)(p + 2048);  R[3] = *(const bf16x8*)(p + 3072); \
        R[4] = *(const bf16x8*)(p2);        R[5] = *(const bf16x8*)(p2 + 1024);\
        R[6] = *(const bf16x8*)(p2 + 2048); R[7] = *(const bf16x8*)(p2 + 3072);\
    } while (0)

#define COMPUTE(R, ACC) do {                                                 \
        __builtin_amdgcn_s_setprio(1);                                       \
        _Pragma("unroll")                                                    \
        for (int m = 0; m < 4; ++m) {                                        \
            ACC[m][0] = __builtin_amdgcn_mfma_f32_16x16x32_bf16(afr[m][0], R[0], fz, 0, 0, 0); \
            ACC[m][1] = __builtin_amdgcn_mfma_f32_16x16x32_bf16(afr[m][0], R[4], fz, 0, 0, 0); \
        }                                                                    \
        _Pragma("unroll")                                                    \
        for (int kk = 1; kk < 4; ++kk) {                                     \
            _Pragma("unroll")                                                \
            for (int m = 0; m < 4; ++m) {                                    \
                ACC[m][0] = __builtin_amdgcn_mfma_f32_16x16x32_bf16(afr[m][kk], R[kk],     ACC[m][0], 0, 0, 0); \
                ACC[m][1] = __builtin_amdgcn_mfma_f32_16x16x32_bf16(afr[m][kk], R[4 + kk], ACC[m][1], 0, 0, 0); \
            }                                                                \
        }                                                                    \
        __builtin_amdgcn_s_setprio(0);                                       \
    } while (0)

#define EXP2S(ACC) do {                                                      \
        _Pragma("unroll")                                                    \
        for (int m = 0; m < 4; ++m)                                          \
            _Pragma("unroll")                                                \
            for (int q = 0; q < 4; ++q)                                      \
                psum[m][q] += exp2_fast(ACC[m][0][q]) + exp2_fast(ACC[m][1][q]); \
    } while (0)

    float psum[4][4];
    #pragma unroll
    for (int m = 0; m < 4; ++m)
        #pragma unroll
        for (int q = 0; q < 4; ++q) psum[m][q] = 0.f;

    const f32x4 fz = {0.f, 0.f, 0.f, 0.f};
    f32x4 accE[4][2], accO[4][2];
    #pragma unroll
    for (int m = 0; m < 4; ++m)
        #pragma unroll
        for (int nn = 0; nn < 2; ++nn)
            accO[m][nn] = (f32x4){-16384.f, -16384.f, -16384.f, -16384.f}; // exp2 -> 0

    bf16x8 RA[8], RB[8];
    LOADSET(RA, 0);
    #pragma unroll 1
    for (int j = 0; j < 96; j += 2) {
        LOADSET(RB, j + 1);          // prefetch next strip
        EXP2S(accO);                 // trans-pipe work of strip j-1 under load latency
        COMPUTE(RA, accE);           // strip j
        LOADSET(RA, j + 2);
        EXP2S(accE);                 // strip j
        COMPUTE(RB, accO);           // strip j+1
    }
    // epilogue: strips 96 (RA already loaded), 97
    LOADSET(RB, 97);
    EXP2S(accO);                     // strip 95
    COMPUTE(RA, accE);               // strip 96
    EXP2S(accE);                     // strip 96
    COMPUTE(RB, accO);               // strip 97
    EXP2S(accO);                     // strip 97

#undef LOADSET
#undef COMPUTE
#undef EXP2S

    // reduce over 16 lanes (same q-rows, different v-cols), then atomics
    #pragma unroll
    for (int m = 0; m < 4; ++m) {
        #pragma unroll
        for (int q = 0; q < 4; ++q) {
            float v = psum[m][q];
            v += __shfl_xor(v, 1);
            v += __shfl_xor(v, 2);
            v += __shfl_xor(v, 4);
            v += __shfl_xor(v, 8);
            if (r0 == 0) {
                int row = qb * 256 + wv * 64 + m * 16 + hi * 4 + q;
                atomicAdd(&Ssum[row], v);
            }
        }
    }
}

// ---- kernel 4: per-row term = log(S - PADROWS) - true_logit ----
// Kn is fragment-major: row lab, byte b=4*lane at
// (lab>>5)*8192 + ((lab>>4)&1)*4096 + (lane>>4)*1024 + ((lane>>2)&3)*256 + (lab&15)*16 + (lane&3)*4
__global__ void term_kernel(const __hip_bfloat16* __restrict__ Qn,
                            const char* __restrict__ Kn,
                            const int* __restrict__ labels,
                            const float* __restrict__ Ssum,
                            float* __restrict__ T) {
    int w = (blockIdx.x * blockDim.x + threadIdx.x) >> 6;
    int lane = threadIdx.x & 63;
    if (w >= N_) return;
    int lab = labels[w];
    __hip_bfloat162 q2 = ((const __hip_bfloat162*)(Qn + (size_t)w * D_))[lane];
    const char* kaddr = Kn + ((size_t)(lab >> 5)) * 8192 + ((lab >> 4) & 1) * 4096
                      + (lane >> 4) * 1024 + ((lane >> 2) & 3) * 256
                      + (lab & 15) * 16 + (lane & 3) * 4;
    __hip_bfloat162 k2 = *(const __hip_bfloat162*)kaddr;
    float d = __bfloat162float(q2.x) * __bfloat162float(k2.x)
            + __bfloat162float(q2.y) * __bfloat162float(k2.y);
    #pragma unroll
    for (int off = 32; off; off >>= 1) d += __shfl_xor(d, off);
    if (lane == 0) T[w] = logf(Ssum[w] - PADROWS_) - d * LN2_;
}

// ---- kernel 5: mean over N ----
__global__ void reduce_kernel(const float* __restrict__ T, float* __restrict__ out) {
    __shared__ float sm[4];
    float s = 0.f;
    for (int i = threadIdx.x; i < N_; i += 256) s += T[i];
    #pragma unroll
    for (int off = 32; off; off >>= 1) s += __shfl_xor(s, off);
    if ((threadIdx.x & 63) == 0) sm[threadIdx.x >> 6] = s;
    __syncthreads();
    if (threadIdx.x == 0) out[0] = (sm[0] + sm[1] + sm[2] + sm[3]) * (1.0f / (float)N_);
}

extern "C" void kernel_launch(void* const* d_in, const int* in_sizes, int n_in,
                              void* d_out, int out_size, void* d_ws, size_t ws_size,
                              hipStream_t stream) {
    (void)in_sizes; (void)n_in; (void)out_size; (void)ws_size;
    const float* Q   = (const float*)d_in[0];
    const float* K   = (const float*)d_in[1];
    const int* loc   = (const int*)d_in[2];
    const int* labels= (const int*)d_in[3];
    float* out = (float*)d_out;

    char* ws = (char*)d_ws;
    char* Kn           = ws;                                        // 3136*8192 = 25,690,112 B
    __hip_bfloat16* Qn = (__hip_bfloat16*)(ws + 25690112);          // N_*128*2  =  1,048,576 B
    float* Ssum        = (float*)(ws + 25690112 + 1048576);         // N_*4
    float* T           = Ssum + N_;                                  // N_*4

    knorm_kernel<<<VSTRIPS_, 256, 0, stream>>>(K, Kn);
    qnorm_kernel<<<N_ / 4, 256, 0, stream>>>(Q, loc, Qn, Ssum);
    ce_main<<<dim3(16, 32), 256, 0, stream>>>(Qn, Kn, Ssum);
    term_kernel<<<N_ / 4, 256, 0, stream>>>(Qn, Kn, labels, Ssum, T);
    reduce_kernel<<<1, 256, 0, stream>>>(T, out);
}